// Round 4
// baseline (456.755 us; speedup 1.0000x reference)
//
#include <hip/hip_runtime.h>

typedef int int32x4 __attribute__((ext_vector_type(4)));

// ---------------------------------------------------------------------------
// maxabs reduction (for weight_scale = max|W| / 7)
// ---------------------------------------------------------------------------
__global__ void maxabs_kernel(const float* __restrict__ x, int n4,
                              unsigned* __restrict__ out) {
    float m = 0.f;
    int i = blockIdx.x * blockDim.x + threadIdx.x;
    int stride = gridDim.x * blockDim.x;
    const float4* x4 = (const float4*)x;
    for (int j = i; j < n4; j += stride) {
        float4 v = x4[j];
        m = fmaxf(m, fmaxf(fmaxf(fabsf(v.x), fabsf(v.y)),
                           fmaxf(fabsf(v.z), fabsf(v.w))));
    }
#pragma unroll
    for (int off = 32; off; off >>= 1)
        m = fmaxf(m, __shfl_down(m, off, 64));
    __shared__ float wm[4];
    int ln = threadIdx.x & 63, wv = threadIdx.x >> 6;
    if (ln == 0) wm[wv] = m;
    __syncthreads();
    if (threadIdx.x == 0) {
        float bm = fmaxf(fmaxf(wm[0], wm[1]), fmaxf(wm[2], wm[3]));
        atomicMax(out, __float_as_uint(bm));  // nonneg floats: bit order ok
    }
}

// ---------------------------------------------------------------------------
// fake-quant to int8 codes: clip(round(x / s), lo, hi), packed 4/thread
// ---------------------------------------------------------------------------
__global__ void quant_kernel(const float* __restrict__ x, int n4,
                             const float* __restrict__ sptr, float sdiv,
                             float lo, float hi, char* __restrict__ out) {
    float s = sptr[0] / sdiv;
    int i = blockIdx.x * blockDim.x + threadIdx.x;
    int stride = gridDim.x * blockDim.x;
    const float4* x4 = (const float4*)x;
    int* o4 = (int*)out;
    for (int j = i; j < n4; j += stride) {
        float4 v = x4[j];
        int a = (int)fminf(fmaxf(rintf(v.x / s), lo), hi);
        int b = (int)fminf(fmaxf(rintf(v.y / s), lo), hi);
        int c = (int)fminf(fmaxf(rintf(v.z / s), lo), hi);
        int d = (int)fminf(fmaxf(rintf(v.w / s), lo), hi);
        o4[j] = (a & 255) | ((b & 255) << 8) | ((c & 255) << 16) | ((d & 255) << 24);
    }
}

// ---------------------------------------------------------------------------
// int8 GEMM, C[m,n] = sum_k A[m,k]*B[n,k] (both row-major [.,K]).
// 256x256 tile, BK=128 B, 512 threads (8 waves: 2 wm x 4 wn), 8-phase
// schedule. LDS per operand: [2 buf][2 kh][256 rows][64 B] = 64 KiB,
// total 128 KiB. Chunk swizzle c ^= (row>>1)&3, source pre-swizzled.
//
// Per K-tile t (buf b=t&1), phases (kh,mh): (0,0)(0,1)(1,0)(1,1); stages:
//   P0: A_kh1(t+1)   P1: B_kh1(t+1)   (other buffer, sealed at t-1 P3)
//   P2: A_kh0(t+2)   P3: B_kh0(t+2)   (buf b kh0, sealed at t's P1 barrier)
// DERIVED WAITS (the round-3 fix): two vmcnt(8) per tile, not one vmcnt(4):
//   P1-end queue = {kh1(t), kh0(t+1), kh1(t+1)} = 12 instrs -> vmcnt(8)
//     forces exactly kh1(t) (needed P2; issued t-1:P0 -> 5 phases slack)
//   P3-end queue = {kh0(t+1), kh1(t+1), kh0(t+2)} = 12 -> vmcnt(8)
//     forces exactly kh0(t+1) (needed t+1:P0; issued t-1:P2 -> 5 phases)
// Never drains below 8 in the main loop (T4).
// ---------------------------------------------------------------------------
#define PHASE(B_, KH_, MH_, LOADB_, STG_, VMC_)                                \
  {                                                                            \
    if (LOADB_) {                                                              \
      _Pragma("unroll")                                                        \
      for (int nf = 0; nf < 4; ++nf)                                           \
        bf[nf] = *(const int32x4*)(&lB[B_][KH_][0] +                           \
                                   (wn * 64 + nf * 16) * 64 + coff);           \
    }                                                                          \
    int32x4 af[4];                                                             \
    _Pragma("unroll")                                                          \
    for (int mf = 0; mf < 4; ++mf)                                             \
      af[mf] = *(const int32x4*)(&lA[B_][KH_][0] +                             \
                                 (wm * 128 + MH_ * 64 + mf * 16) * 64 + coff); \
    STG_;                                                                      \
    __builtin_amdgcn_s_barrier();                                              \
    asm volatile("s_waitcnt lgkmcnt(0)" ::: "memory");                         \
    __builtin_amdgcn_sched_barrier(0);                                         \
    __builtin_amdgcn_s_setprio(1);                                             \
    _Pragma("unroll")                                                          \
    for (int mf = 0; mf < 4; ++mf)                                             \
      _Pragma("unroll")                                                        \
      for (int nf = 0; nf < 4; ++nf)                                           \
        acc[MH_ * 4 + mf][nf] = __builtin_amdgcn_mfma_i32_16x16x64_i8(         \
            af[mf], bf[nf], acc[MH_ * 4 + mf][nf], 0, 0, 0);                   \
    __builtin_amdgcn_s_setprio(0);                                             \
    VMC_;                                                                      \
    __builtin_amdgcn_s_barrier();                                              \
  }

template <bool FIRST>
__global__ __launch_bounds__(512, 2)
void gemm_i8_kernel(const char* __restrict__ A, const char* __restrict__ B,
                    int M, int N, int K,
                    const float* __restrict__ sa_ptr,
                    const float* __restrict__ wmax_ptr,
                    const float* __restrict__ bias,
                    const float* __restrict__ s2_ptr,
                    char* __restrict__ out8, float* __restrict__ outf) {
    __shared__ __align__(16) char lA[2][2][256 * 64];  // 64 KiB
    __shared__ __align__(16) char lB[2][2][256 * 64];  // 64 KiB

    const int tid = threadIdx.x;
    const int wv = tid >> 6, ln = tid & 63;
    const int lo = ln & 15, hi = ln >> 4;
    const int wm = wv >> 2, wn = wv & 3;
    const long m0 = (long)blockIdx.y * 256;
    const long n0 = (long)blockIdx.x * 256;

    int32x4 acc[8][4] = {};
    int32x4 bf[4];
    // frag read offset within a [256][64] slab; (row>>1)&3 == (lo>>1)&3
    const int coff = lo * 64 + ((hi ^ ((lo >> 1) & 3)) << 4);

    const int nkt = K >> 7;  // K-tiles of 128 B

    // stage one (operand, tile, kh) 16 KiB half-slab: 2 loads/thread,
    // wave-uniform LDS base + lane*16; global source pre-swizzled.
    auto stg_a = [&](int t, int kh) {
#pragma unroll
        for (int r = 0; r < 2; ++r) {
            int s = r * 512 + tid;
            int row = s >> 2;
            int c = (s & 3) ^ ((row >> 1) & 3);
            long g = (m0 + row) * K + ((long)t << 7) + (kh << 6) + c * 16;
            __builtin_amdgcn_global_load_lds(
                (const __attribute__((address_space(1))) void*)(A + g),
                (__attribute__((address_space(3))) void*)(
                    &lA[t & 1][kh][0] + (r * 512 + wv * 64) * 16), 16, 0, 0);
        }
    };
    auto stg_b = [&](int t, int kh) {
#pragma unroll
        for (int r = 0; r < 2; ++r) {
            int s = r * 512 + tid;
            int row = s >> 2;
            int c = (s & 3) ^ ((row >> 1) & 3);
            long g = (n0 + row) * K + ((long)t << 7) + (kh << 6) + c * 16;
            __builtin_amdgcn_global_load_lds(
                (const __attribute__((address_space(1))) void*)(B + g),
                (__attribute__((address_space(3))) void*)(
                    &lB[t & 1][kh][0] + (r * 512 + wv * 64) * 16), 16, 0, 0);
        }
    };

    // prologue: 6 stages in flight (12 instrs); vmcnt(8) forces kh0(0) only
    stg_a(0, 0); stg_b(0, 0);
    stg_a(0, 1); stg_b(0, 1);
    stg_a(1, 0); stg_b(1, 0);
    asm volatile("s_waitcnt vmcnt(8)" ::: "memory");
    __builtin_amdgcn_s_barrier();

    for (int t = 0; t < nkt - 2; ++t) {
        const int b = t & 1;
        PHASE(b, 0, 0, true,  stg_a(t + 1, 1), );
        PHASE(b, 0, 1, false, stg_b(t + 1, 1),
              asm volatile("s_waitcnt vmcnt(8)" ::: "memory"));
        PHASE(b, 1, 0, true,  stg_a(t + 2, 0), );
        PHASE(b, 1, 1, false, stg_b(t + 2, 0),
              asm volatile("s_waitcnt vmcnt(8)" ::: "memory"));
    }
    {   // t = nkt-2: stage only kh1(nkt-1); waits 8 -> 4
        const int t = nkt - 2, b = t & 1;
        PHASE(b, 0, 0, true,  stg_a(t + 1, 1), );
        PHASE(b, 0, 1, false, stg_b(t + 1, 1),
              asm volatile("s_waitcnt vmcnt(8)" ::: "memory"));
        PHASE(b, 1, 0, true,  , );
        PHASE(b, 1, 1, false, ,
              asm volatile("s_waitcnt vmcnt(4)" ::: "memory"));
    }
    {   // t = nkt-1: compute only; drain kh1(nkt-1) at P1
        const int b = (nkt - 1) & 1;
        PHASE(b, 0, 0, true,  , );
        PHASE(b, 0, 1, false, ,
              asm volatile("s_waitcnt vmcnt(0)" ::: "memory"));
        PHASE(b, 1, 0, true,  , );
        PHASE(b, 1, 1, false, , );
    }

    // ---- epilogue (same C/D mapping as verified rounds 1-3) ----
    float sa = sa_ptr[0];
    float sw = wmax_ptr[0] / 7.0f;
    float sab = sa * sw;
    float s2v = FIRST ? s2_ptr[0] : 0.f;

#pragma unroll
    for (int nf = 0; nf < 4; ++nf) {
        long col = n0 + wn * 64 + nf * 16 + lo;
        float bq = rintf(bias[col] / sab) * sab;  // Int32Bias fake-quant
#pragma unroll
        for (int am = 0; am < 8; ++am) {
            long rbase = m0 + wm * 128 + (am >> 2) * 64 + (am & 3) * 16 + (hi << 2);
#pragma unroll
            for (int i = 0; i < 4; ++i) {
                float h = sab * (float)acc[am][nf][i] + bq;
                long off = (rbase + i) * N + col;
                if constexpr (FIRST) {
                    h = fmaxf(h, 0.f);
                    float q = fminf(fmaxf(rintf(h / s2v), 0.f), 15.f);
                    out8[off] = (char)(int)q;
                } else {
                    outf[off] = h;
                }
            }
        }
    }
}

// ---------------------------------------------------------------------------
// launch
// ---------------------------------------------------------------------------
extern "C" void kernel_launch(void* const* d_in, const int* in_sizes, int n_in,
                              void* d_out, int out_size, void* d_ws, size_t ws_size,
                              hipStream_t stream) {
    const float* x  = (const float*)d_in[0];   // [4,2048,2048] -> [8192,2048]
    const float* W1 = (const float*)d_in[1];   // [8192,2048]
    const float* b1 = (const float*)d_in[2];   // [8192]
    const float* W2 = (const float*)d_in[3];   // [2048,8192]
    const float* b2 = (const float*)d_in[4];   // [2048]
    const float* s1 = (const float*)d_in[5];
    const float* s2 = (const float*)d_in[6];

    const int M = 8192, D = 2048, F = 8192;

    char* ws = (char*)d_ws;
    unsigned* mx1 = (unsigned*)ws;        // maxabs(W1) as float bits
    unsigned* mx2 = (unsigned*)(ws + 4);  // maxabs(W2)
    char* xq  = ws + 256;                  // [M,D]  int8
    char* w1q = xq + (size_t)M * D;        // [F,D]  int8
    char* w2q = w1q + (size_t)F * D;       // [D,F]  int8
    char* hq  = w2q + (size_t)D * F;       // [M,F]  int8 (h_q codes 0..15)

    hipMemsetAsync(d_ws, 0, 8, stream);   // zero the maxabs slots

    maxabs_kernel<<<2048, 256, 0, stream>>>(W1, (F * D) >> 2, mx1);
    maxabs_kernel<<<2048, 256, 0, stream>>>(W2, (D * F) >> 2, mx2);

    quant_kernel<<<2048, 256, 0, stream>>>(x,  (M * D) >> 2, s1, 1.f, -8.f, 7.f, xq);
    quant_kernel<<<2048, 256, 0, stream>>>(W1, (F * D) >> 2, (const float*)mx1, 7.f, -8.f, 7.f, w1q);
    quant_kernel<<<2048, 256, 0, stream>>>(W2, (D * F) >> 2, (const float*)mx2, 7.f, -8.f, 7.f, w2q);

    gemm_i8_kernel<true><<<dim3(F / 256, M / 256), 512, 0, stream>>>(
        xq, w1q, M, F, D, s1, (const float*)mx1, b1, s2, hq, nullptr);

    gemm_i8_kernel<false><<<dim3(D / 256, M / 256), 512, 0, stream>>>(
        hq, w2q, M, D, F, s2, (const float*)mx2, b2, nullptr, nullptr, (float*)d_out);
}

// Round 5
// 429.589 us; speedup vs baseline: 1.0632x; 1.0632x over previous
//
#include <hip/hip_runtime.h>

typedef int int32x4 __attribute__((ext_vector_type(4)));
typedef int int32x16 __attribute__((ext_vector_type(16)));

// ---------------------------------------------------------------------------
// maxabs reduction (for weight_scale = max|W| / 7)
// ---------------------------------------------------------------------------
__global__ void maxabs_kernel(const float* __restrict__ x, int n4,
                              unsigned* __restrict__ out) {
    float m = 0.f;
    int i = blockIdx.x * blockDim.x + threadIdx.x;
    int stride = gridDim.x * blockDim.x;
    const float4* x4 = (const float4*)x;
    for (int j = i; j < n4; j += stride) {
        float4 v = x4[j];
        m = fmaxf(m, fmaxf(fmaxf(fabsf(v.x), fabsf(v.y)),
                           fmaxf(fabsf(v.z), fabsf(v.w))));
    }
#pragma unroll
    for (int off = 32; off; off >>= 1)
        m = fmaxf(m, __shfl_down(m, off, 64));
    __shared__ float wm[4];
    int ln = threadIdx.x & 63, wv = threadIdx.x >> 6;
    if (ln == 0) wm[wv] = m;
    __syncthreads();
    if (threadIdx.x == 0) {
        float bm = fmaxf(fmaxf(wm[0], wm[1]), fmaxf(wm[2], wm[3]));
        atomicMax(out, __float_as_uint(bm));  // nonneg floats: bit order ok
    }
}

// ---------------------------------------------------------------------------
// fake-quant to int8 codes: clip(round(x / s), lo, hi), packed 4/thread
// ---------------------------------------------------------------------------
__global__ void quant_kernel(const float* __restrict__ x, int n4,
                             const float* __restrict__ sptr, float sdiv,
                             float lo, float hi, char* __restrict__ out) {
    float s = sptr[0] / sdiv;
    int i = blockIdx.x * blockDim.x + threadIdx.x;
    int stride = gridDim.x * blockDim.x;
    const float4* x4 = (const float4*)x;
    int* o4 = (int*)out;
    for (int j = i; j < n4; j += stride) {
        float4 v = x4[j];
        int a = (int)fminf(fmaxf(rintf(v.x / s), lo), hi);
        int b = (int)fminf(fmaxf(rintf(v.y / s), lo), hi);
        int c = (int)fminf(fmaxf(rintf(v.z / s), lo), hi);
        int d = (int)fminf(fmaxf(rintf(v.w / s), lo), hi);
        o4[j] = (a & 255) | ((b & 255) << 8) | ((c & 255) << 16) | ((d & 255) << 24);
    }
}

// ---------------------------------------------------------------------------
// int8 GEMM, C[m,n] = sum_k A[m,k]*B[n,k]  (both row-major [.,K]).
// Round-1 skeleton (verified 42% MfmaUtil, ~3 blocks/CU implicit overlap):
// 128x128 tile, BK=128 B, 4 waves (2x2, each 64x64), single-buffer LDS
// (2 x 16 KiB), global_load_lds width=16 with pre-swizzled source (rule #21),
// chunk swizzle c ^= row&7 (optimal: 8 words/bank = b128 inherent minimum).
// CHANGED vs round 1: mfma_i32_32x32x32_i8 (2x2 frags x 4 ksteps = 16 MFMA
// per K-tile, half the issue slots, +12% ceiling) and XCD-bijective block
// swizzle (T1/m204) for L2 A-panel reuse.
// C/D layout (m74/m101, dtype-independent):
//   col = lane&31, row = (reg&3) + 8*(reg>>2) + 4*(lane>>5).
// ---------------------------------------------------------------------------
template <bool FIRST>
__global__ __launch_bounds__(256, 2)
void gemm_i8_kernel(const char* __restrict__ A, const char* __restrict__ B,
                    int M, int N, int K,
                    const float* __restrict__ sa_ptr,
                    const float* __restrict__ wmax_ptr,
                    const float* __restrict__ bias,
                    const float* __restrict__ s2_ptr,
                    char* __restrict__ out8, float* __restrict__ outf) {
    __shared__ __align__(16) char lA[128 * 128];
    __shared__ __align__(16) char lB[128 * 128];

    const int tid = threadIdx.x;
    const int wv = tid >> 6, ln = tid & 63;
    const int l31 = ln & 31, hi5 = ln >> 5;
    const int wr = wv >> 1, wc = wv & 1;

    // ---- T1: bijective XCD swizzle (m204) ----
    const int gx = gridDim.x;
    const int nwg = gx * gridDim.y;
    const int orig = blockIdx.y * gx + blockIdx.x;
    const int q = nwg >> 3, r8 = nwg & 7;
    const int xcd = orig & 7, idx = orig >> 3;
    const int wg = (xcd < r8 ? xcd * (q + 1) : r8 * (q + 1) + (xcd - r8) * q) + idx;
    const long m0 = (long)(wg / gx) * 128;
    const long n0 = (long)(wg % gx) * 128;

    int32x16 acc[2][2] = {};

    const int nkt = K >> 7;
    for (int kt = 0; kt < nkt; ++kt) {
        const long k0 = (long)kt << 7;
        // ---- stage A and B tiles (16 KiB each) — identical to round 1 ----
#pragma unroll
        for (int r = 0; r < 4; ++r) {
            int s = r * 256 + tid;     // 16B slot index 0..1023
            int row = s >> 3;          // 8 slots per 128B row
            int ch = s & 7;
            int sch = ch ^ (row & 7);  // pre-swizzle the SOURCE (m173)
            long ga = (m0 + row) * K + k0 + sch * 16;
            long gb = (n0 + row) * K + k0 + sch * 16;
            int lbase = (r * 256 + wv * 64) * 16;  // wave-uniform LDS base
            __builtin_amdgcn_global_load_lds(
                (const __attribute__((address_space(1))) void*)(A + ga),
                (__attribute__((address_space(3))) void*)(lA + lbase), 16, 0, 0);
            __builtin_amdgcn_global_load_lds(
                (const __attribute__((address_space(1))) void*)(B + gb),
                (__attribute__((address_space(3))) void*)(lB + lbase), 16, 0, 0);
        }
        __syncthreads();

        // ---- LDS -> fragments (swizzled read), 32x32 layout ----
        // A frag (fm, ks): row = wr*64 + fm*32 + l31, chunk = ks*2 + hi5
        int32x4 af[2][4], bf[2][4];
#pragma unroll
        for (int fm = 0; fm < 2; ++fm)
#pragma unroll
            for (int ks = 0; ks < 4; ++ks) {
                int row = wr * 64 + fm * 32 + l31;
                int ch = ks * 2 + hi5;
                af[fm][ks] = *(const int32x4*)(lA + row * 128 + ((ch ^ (row & 7)) * 16));
            }
#pragma unroll
        for (int fn = 0; fn < 2; ++fn)
#pragma unroll
            for (int ks = 0; ks < 4; ++ks) {
                int col = wc * 64 + fn * 32 + l31;
                int ch = ks * 2 + hi5;
                bf[fn][ks] = *(const int32x4*)(lB + col * 128 + ((ch ^ (col & 7)) * 16));
            }

        // ---- MFMA: 16 x 32x32x32 i8 ----
#pragma unroll
        for (int ks = 0; ks < 4; ++ks)
#pragma unroll
            for (int fm = 0; fm < 2; ++fm)
#pragma unroll
                for (int fn = 0; fn < 2; ++fn)
                    acc[fm][fn] = __builtin_amdgcn_mfma_i32_32x32x32_i8(
                        af[fm][ks], bf[fn][ks], acc[fm][fn], 0, 0, 0);
        __syncthreads();
    }

    // ---- epilogue (32x32 C/D mapping) ----
    float sa = sa_ptr[0];
    float sw = wmax_ptr[0] / 7.0f;  // weight_scale
    float sab = sa * sw;
    float s2v = FIRST ? s2_ptr[0] : 0.f;

#pragma unroll
    for (int fn = 0; fn < 2; ++fn) {
        long col = n0 + wc * 64 + fn * 32 + l31;
        float bq = rintf(bias[col] / sab) * sab;  // Int32Bias fake-quant
#pragma unroll
        for (int fm = 0; fm < 2; ++fm) {
            long rbase = m0 + wr * 64 + fm * 32 + 4 * hi5;
#pragma unroll
            for (int reg = 0; reg < 16; ++reg) {
                long row = rbase + (reg & 3) + 8 * (reg >> 2);
                float h = sab * (float)acc[fm][fn][reg] + bq;
                long off = row * N + col;
                if constexpr (FIRST) {
                    h = fmaxf(h, 0.f);
                    float qv = fminf(fmaxf(rintf(h / s2v), 0.f), 15.f);
                    out8[off] = (char)(int)qv;
                } else {
                    outf[off] = h;
                }
            }
        }
    }
}

// ---------------------------------------------------------------------------
// launch
// ---------------------------------------------------------------------------
extern "C" void kernel_launch(void* const* d_in, const int* in_sizes, int n_in,
                              void* d_out, int out_size, void* d_ws, size_t ws_size,
                              hipStream_t stream) {
    const float* x  = (const float*)d_in[0];   // [4,2048,2048] -> [8192,2048]
    const float* W1 = (const float*)d_in[1];   // [8192,2048]
    const float* b1 = (const float*)d_in[2];   // [8192]
    const float* W2 = (const float*)d_in[3];   // [2048,8192]
    const float* b2 = (const float*)d_in[4];   // [2048]
    const float* s1 = (const float*)d_in[5];
    const float* s2 = (const float*)d_in[6];

    const int M = 8192, D = 2048, F = 8192;

    char* ws = (char*)d_ws;
    unsigned* mx1 = (unsigned*)ws;        // maxabs(W1) as float bits
    unsigned* mx2 = (unsigned*)(ws + 4);  // maxabs(W2)
    char* xq  = ws + 256;                  // [M,D]  int8
    char* w1q = xq + (size_t)M * D;        // [F,D]  int8
    char* w2q = w1q + (size_t)F * D;       // [D,F]  int8
    char* hq  = w2q + (size_t)D * F;       // [M,F]  int8 (h_q codes 0..15)

    hipMemsetAsync(d_ws, 0, 8, stream);   // zero the maxabs slots

    maxabs_kernel<<<2048, 256, 0, stream>>>(W1, (F * D) >> 2, mx1);
    maxabs_kernel<<<2048, 256, 0, stream>>>(W2, (D * F) >> 2, mx2);

    quant_kernel<<<2048, 256, 0, stream>>>(x,  (M * D) >> 2, s1, 1.f, -8.f, 7.f, xq);
    quant_kernel<<<2048, 256, 0, stream>>>(W1, (F * D) >> 2, (const float*)mx1, 7.f, -8.f, 7.f, w1q);
    quant_kernel<<<2048, 256, 0, stream>>>(W2, (D * F) >> 2, (const float*)mx2, 7.f, -8.f, 7.f, w2q);

    // h_q = clip(round(relu(x_q W1_q^T + b1_q)/s2),0,15)  -> int8 codes
    gemm_i8_kernel<true><<<dim3(F / 128, M / 128), 256, 0, stream>>>(
        xq, w1q, M, F, D, s1, (const float*)mx1, b1, s2, hq, nullptr);

    // out = s2*sw2 * (h_int W2_int^T) + b2_q
    gemm_i8_kernel<false><<<dim3(D / 128, M / 128), 256, 0, stream>>>(
        hq, w2q, M, D, F, s2, (const float*)mx2, b2, nullptr, nullptr, (float*)d_out);
}

// Round 6
// 415.829 us; speedup vs baseline: 1.0984x; 1.0331x over previous
//
#include <hip/hip_runtime.h>

typedef int int32x4 __attribute__((ext_vector_type(4)));

// ---------------------------------------------------------------------------
// maxabs reduction (for weight_scale = max|W| / 7)
// ---------------------------------------------------------------------------
__global__ void maxabs_kernel(const float* __restrict__ x, int n4,
                              unsigned* __restrict__ out) {
    float m = 0.f;
    int i = blockIdx.x * blockDim.x + threadIdx.x;
    int stride = gridDim.x * blockDim.x;
    const float4* x4 = (const float4*)x;
    for (int j = i; j < n4; j += stride) {
        float4 v = x4[j];
        m = fmaxf(m, fmaxf(fmaxf(fabsf(v.x), fabsf(v.y)),
                           fmaxf(fabsf(v.z), fabsf(v.w))));
    }
#pragma unroll
    for (int off = 32; off; off >>= 1)
        m = fmaxf(m, __shfl_down(m, off, 64));
    __shared__ float wm[4];
    int ln = threadIdx.x & 63, wv = threadIdx.x >> 6;
    if (ln == 0) wm[wv] = m;
    __syncthreads();
    if (threadIdx.x == 0) {
        float bm = fmaxf(fmaxf(wm[0], wm[1]), fmaxf(wm[2], wm[3]));
        atomicMax(out, __float_as_uint(bm));  // nonneg floats: bit order ok
    }
}

// ---------------------------------------------------------------------------
// fake-quant to int8 codes: clip(round(x / s), lo, hi), packed 4/thread
// ---------------------------------------------------------------------------
__global__ void quant_kernel(const float* __restrict__ x, int n4,
                             const float* __restrict__ sptr, float sdiv,
                             float lo, float hi, char* __restrict__ out) {
    float s = sptr[0] / sdiv;
    int i = blockIdx.x * blockDim.x + threadIdx.x;
    int stride = gridDim.x * blockDim.x;
    const float4* x4 = (const float4*)x;
    int* o4 = (int*)out;
    for (int j = i; j < n4; j += stride) {
        float4 v = x4[j];
        int a = (int)fminf(fmaxf(rintf(v.x / s), lo), hi);
        int b = (int)fminf(fmaxf(rintf(v.y / s), lo), hi);
        int c = (int)fminf(fmaxf(rintf(v.z / s), lo), hi);
        int d = (int)fminf(fmaxf(rintf(v.w / s), lo), hi);
        o4[j] = (a & 255) | ((b & 255) << 8) | ((c & 255) << 16) | ((d & 255) << 24);
    }
}

// ---------------------------------------------------------------------------
// int8 GEMM, C[m,n] = sum_k A[m,k]*B[n,k]  (both row-major [.,K]).
// Round-1 verified skeleton scaled to 256x256: BK=128 B, 8 waves (2 wm x 4
// wn, wave-tile 128x64), 16x16x64 MFMA with the 0-conflict 16-row fragment
// read pattern, chunk swizzle c ^= row&7, source pre-swizzled (rule #21).
// NO XCD swizzle (round-5: FETCH 98->460 MB), NO 32x32 frags (round-5:
// 1.7e7 bank conflicts).
// T3-minimum 2-phase: double-buffered LDS (2 x 64 KiB), stage(t+1) issued
// FIRST, then s_waitcnt vmcnt(8) (forces tile t landed, leaves t+1's 8
// loads in flight -> ~650 cy of MFMA slack), barrier, 64 MFMA under
// setprio, end barrier. 2 barriers + 1 counted vmcnt per K-tile.
// Mechanism: LDS bytes/MAC drop 1.5x vs 128^2 (cap 42% -> ~65% MfmaUtil),
// L2-fill panel traffic halves (2 GB -> 1 GB per GEMM).
// ---------------------------------------------------------------------------
template <bool FIRST>
__global__ __launch_bounds__(512, 2)
void gemm_i8_kernel(const char* __restrict__ A, const char* __restrict__ B,
                    int M, int N, int K,
                    const float* __restrict__ sa_ptr,
                    const float* __restrict__ wmax_ptr,
                    const float* __restrict__ bias,
                    const float* __restrict__ s2_ptr,
                    char* __restrict__ out8, float* __restrict__ outf) {
    __shared__ __align__(16) char lA[2][256 * 128];  // 64 KiB
    __shared__ __align__(16) char lB[2][256 * 128];  // 64 KiB

    const int tid = threadIdx.x;
    const int wv = tid >> 6, ln = tid & 63;
    const int lnlo = ln & 15, lnhi = ln >> 4;
    const int wr = wv >> 2, wn = wv & 3;       // 2 x 4 wave grid
    const long m0 = (long)blockIdx.y * 256;
    const long n0 = (long)blockIdx.x * 256;

    int32x4 acc[8][4] = {};                    // wave-tile 128 x 64

    const int nkt = K >> 7;                    // K-tiles of 128 B

    // stage tile t into buffer t&1: 8 loads/thread (4 A + 4 B), 16 B each,
    // wave-uniform LDS base + lane*16; global source pre-swizzled.
    auto stage = [&](int t) {
        const int buf = t & 1;
        const long k0 = (long)t << 7;
#pragma unroll
        for (int r = 0; r < 4; ++r) {
            int s = r * 512 + tid;     // 16B slot 0..2047
            int row = s >> 3;          // 8 chunks per 128B row
            int ch = s & 7;
            int sch = ch ^ (row & 7);  // inverse swizzle on source (m173)
            long ga = (m0 + row) * K + k0 + sch * 16;
            long gb = (n0 + row) * K + k0 + sch * 16;
            int lbase = (r * 512 + wv * 64) * 16;
            __builtin_amdgcn_global_load_lds(
                (const __attribute__((address_space(1))) void*)(A + ga),
                (__attribute__((address_space(3))) void*)(lA[buf] + lbase), 16, 0, 0);
            __builtin_amdgcn_global_load_lds(
                (const __attribute__((address_space(1))) void*)(B + gb),
                (__attribute__((address_space(3))) void*)(lB[buf] + lbase), 16, 0, 0);
        }
    };

    stage(0);

    for (int t = 0; t < nkt; ++t) {
        if (t + 1 < nkt) {
            stage(t + 1);  // issue next tile BEFORE waiting on current
            asm volatile("s_waitcnt vmcnt(8)" ::: "memory");  // t landed, t+1 flies
        } else {
            asm volatile("s_waitcnt vmcnt(0)" ::: "memory");
        }
        __builtin_amdgcn_s_barrier();
        __builtin_amdgcn_sched_barrier(0);

        const char* la = lA[t & 1];
        const char* lb = lB[t & 1];
        __builtin_amdgcn_s_setprio(1);
#pragma unroll
        for (int kk = 0; kk < 2; ++kk) {
            // 16-row fragment pattern — measured 0 bank conflicts (r1)
            int32x4 af[8], bf[4];
#pragma unroll
            for (int mf = 0; mf < 8; ++mf) {
                int row = wr * 128 + mf * 16 + lnlo;
                int ch = kk * 4 + lnhi;
                af[mf] = *(const int32x4*)(la + row * 128 + ((ch ^ (row & 7)) * 16));
            }
#pragma unroll
            for (int nf = 0; nf < 4; ++nf) {
                int col = wn * 64 + nf * 16 + lnlo;
                int ch = kk * 4 + lnhi;
                bf[nf] = *(const int32x4*)(lb + col * 128 + ((ch ^ (col & 7)) * 16));
            }
#pragma unroll
            for (int mf = 0; mf < 8; ++mf)
#pragma unroll
                for (int nf = 0; nf < 4; ++nf)
                    acc[mf][nf] = __builtin_amdgcn_mfma_i32_16x16x64_i8(
                        af[mf], bf[nf], acc[mf][nf], 0, 0, 0);
        }
        __builtin_amdgcn_s_setprio(0);
        __builtin_amdgcn_s_barrier();  // seal reads of buf[t&1] before t+2 stage
    }

    // ---- epilogue (same verified 16x16 C/D mapping as round 1) ----
    float sa = sa_ptr[0];
    float sw = wmax_ptr[0] / 7.0f;  // weight_scale
    float sab = sa * sw;
    float s2v = FIRST ? s2_ptr[0] : 0.f;

#pragma unroll
    for (int nf = 0; nf < 4; ++nf) {
        long col = n0 + wn * 64 + nf * 16 + lnlo;
        float bq = rintf(bias[col] / sab) * sab;  // Int32Bias fake-quant
#pragma unroll
        for (int mf = 0; mf < 8; ++mf) {
            long rbase = m0 + wr * 128 + mf * 16 + (lnhi << 2);
#pragma unroll
            for (int i = 0; i < 4; ++i) {
                float h = sab * (float)acc[mf][nf][i] + bq;
                long off = (rbase + i) * N + col;
                if constexpr (FIRST) {
                    h = fmaxf(h, 0.f);
                    float qv = fminf(fmaxf(rintf(h / s2v), 0.f), 15.f);
                    out8[off] = (char)(int)qv;
                } else {
                    outf[off] = h;
                }
            }
        }
    }
}

// ---------------------------------------------------------------------------
// launch
// ---------------------------------------------------------------------------
extern "C" void kernel_launch(void* const* d_in, const int* in_sizes, int n_in,
                              void* d_out, int out_size, void* d_ws, size_t ws_size,
                              hipStream_t stream) {
    const float* x  = (const float*)d_in[0];   // [4,2048,2048] -> [8192,2048]
    const float* W1 = (const float*)d_in[1];   // [8192,2048]
    const float* b1 = (const float*)d_in[2];   // [8192]
    const float* W2 = (const float*)d_in[3];   // [2048,8192]
    const float* b2 = (const float*)d_in[4];   // [2048]
    const float* s1 = (const float*)d_in[5];
    const float* s2 = (const float*)d_in[6];

    const int M = 8192, D = 2048, F = 8192;

    char* ws = (char*)d_ws;
    unsigned* mx1 = (unsigned*)ws;        // maxabs(W1) as float bits
    unsigned* mx2 = (unsigned*)(ws + 4);  // maxabs(W2)
    char* xq  = ws + 256;                  // [M,D]  int8
    char* w1q = xq + (size_t)M * D;        // [F,D]  int8
    char* w2q = w1q + (size_t)F * D;       // [D,F]  int8
    char* hq  = w2q + (size_t)D * F;       // [M,F]  int8 (h_q codes 0..15)

    hipMemsetAsync(d_ws, 0, 8, stream);   // zero the maxabs slots

    maxabs_kernel<<<2048, 256, 0, stream>>>(W1, (F * D) >> 2, mx1);
    maxabs_kernel<<<2048, 256, 0, stream>>>(W2, (D * F) >> 2, mx2);

    quant_kernel<<<2048, 256, 0, stream>>>(x,  (M * D) >> 2, s1, 1.f, -8.f, 7.f, xq);
    quant_kernel<<<2048, 256, 0, stream>>>(W1, (F * D) >> 2, (const float*)mx1, 7.f, -8.f, 7.f, w1q);
    quant_kernel<<<2048, 256, 0, stream>>>(W2, (D * F) >> 2, (const float*)mx2, 7.f, -8.f, 7.f, w2q);

    // h_q = clip(round(relu(x_q W1_q^T + b1_q)/s2),0,15)  -> int8 codes
    gemm_i8_kernel<true><<<dim3(F / 256, M / 256), 512, 0, stream>>>(
        xq, w1q, M, F, D, s1, (const float*)mx1, b1, s2, hq, nullptr);

    // out = s2*sw2 * (h_int W2_int^T) + b2_q
    gemm_i8_kernel<false><<<dim3(D / 256, M / 256), 512, 0, stream>>>(
        hq, w2q, M, D, F, s2, (const float*)mx2, b2, nullptr, nullptr, (float*)d_out);
}

// Round 7
// 381.977 us; speedup vs baseline: 1.1958x; 1.0886x over previous
//
#include <hip/hip_runtime.h>

typedef int int32x4 __attribute__((ext_vector_type(4)));

// ---------------------------------------------------------------------------
// maxabs reduction (for weight_scale = max|W| / 7)
// ---------------------------------------------------------------------------
__global__ void maxabs_kernel(const float* __restrict__ x, int n4,
                              unsigned* __restrict__ out) {
    float m = 0.f;
    int i = blockIdx.x * blockDim.x + threadIdx.x;
    int stride = gridDim.x * blockDim.x;
    const float4* x4 = (const float4*)x;
    for (int j = i; j < n4; j += stride) {
        float4 v = x4[j];
        m = fmaxf(m, fmaxf(fmaxf(fabsf(v.x), fabsf(v.y)),
                           fmaxf(fabsf(v.z), fabsf(v.w))));
    }
#pragma unroll
    for (int off = 32; off; off >>= 1)
        m = fmaxf(m, __shfl_down(m, off, 64));
    __shared__ float wm[4];
    int ln = threadIdx.x & 63, wv = threadIdx.x >> 6;
    if (ln == 0) wm[wv] = m;
    __syncthreads();
    if (threadIdx.x == 0) {
        float bm = fmaxf(fmaxf(wm[0], wm[1]), fmaxf(wm[2], wm[3]));
        atomicMax(out, __float_as_uint(bm));  // nonneg floats: bit order ok
    }
}

// ---------------------------------------------------------------------------
// fake-quant to int8 codes in BLOCKED-PRESWIZZLED layout:
//   out[blk][row][c][b] (16384 B blocks, blk = rowblk*(K/128)+kblk)
//   stored[row][c] = orig[row][c ^ (row&7)]  (the exact LDS image the GEMM
//   expects, so GEMM staging is a contiguous 16 KB copy, rule #21).
// One thread per 4 output bytes (one float4 read, 16-B aligned).
// ---------------------------------------------------------------------------
__global__ void quant_blocked_kernel(const float* __restrict__ src, int n4,
                                     int K, int kshift,
                                     const float* __restrict__ sptr, float sdiv,
                                     float lo, float hi, int* __restrict__ out) {
    float s = sptr[0] / sdiv;
    int i0 = blockIdx.x * blockDim.x + threadIdx.x;
    int stride = gridDim.x * blockDim.x;
    for (int o = i0; o < n4; o += stride) {
        int blk = o >> 12;            // 4096 int-groups per 16 KB block
        int i = o & 4095;
        int row = i >> 5;             // 32 groups per 128-B row
        int c = (i >> 2) & 7;         // stored 16-B chunk
        int b4 = i & 3;               // float4 within chunk
        int rowblk = blk >> kshift;
        int kblk = blk & ((1 << kshift) - 1);
        int co = c ^ (row & 7);       // original chunk
        long srcoff = (long)(rowblk * 128 + row) * K + (kblk << 7) + (co << 4) + (b4 << 2);
        float4 v = *(const float4*)(src + srcoff);
        int a = (int)fminf(fmaxf(rintf(v.x / s), lo), hi);
        int b = (int)fminf(fmaxf(rintf(v.y / s), lo), hi);
        int cc = (int)fminf(fmaxf(rintf(v.z / s), lo), hi);
        int d = (int)fminf(fmaxf(rintf(v.w / s), lo), hi);
        out[o] = (a & 255) | ((b & 255) << 8) | ((cc & 255) << 16) | ((d & 255) << 24);
    }
}

// ---------------------------------------------------------------------------
// int8 GEMM, C[m,n] = sum_k A[m,k]*B[n,k], operands in blocked-preswizzled
// layout ([rowblk][kblk][16384 B]). Round-1 verified compute structure:
// 128x128 tile, BK=128 B, 4 waves (2x2), single-buffer 32 KiB LDS,
// 16x16x64 MFMA, 0-conflict swizzled ds_read_b128, 2 barriers/K-tile.
// CHANGED vs round 1: staging is a contiguous 16 KB copy (base + s*16,
// one pointer bump per K-tile) -> VALU address math off the critical path.
// FIRST epilogue writes hq in blocked-preswizzled layout for GEMM2.
// ---------------------------------------------------------------------------
template <bool FIRST>
__global__ __launch_bounds__(256, 2)
void gemm_i8_kernel(const char* __restrict__ A, const char* __restrict__ B,
                    int N, int nkt,
                    const float* __restrict__ sa_ptr,
                    const float* __restrict__ wmax_ptr,
                    const float* __restrict__ bias,
                    const float* __restrict__ s2_ptr,
                    char* __restrict__ out8, float* __restrict__ outf) {
    __shared__ __align__(16) char lA[128 * 128];
    __shared__ __align__(16) char lB[128 * 128];

    const int tid = threadIdx.x;
    const int wv = tid >> 6, ln = tid & 63;
    const int lnlo = ln & 15, lnhi = ln >> 4;
    const int wr = wv >> 1, wc = wv & 1;

    int32x4 acc[4][4] = {};

    // blocked operand bases: block index = rowblk*nkt + kt
    const char* pa = A + ((size_t)blockIdx.y * nkt << 14);
    const char* pb = B + ((size_t)blockIdx.x * nkt << 14);

    for (int kt = 0; kt < nkt; ++kt) {
        // ---- stage: contiguous 16 KB copy per operand ----
#pragma unroll
        for (int r = 0; r < 4; ++r) {
            int off = (r * 256 + tid) * 16;
            int lbase = (r * 256 + wv * 64) * 16;  // wave-uniform base (+ln*16 by HW)
            __builtin_amdgcn_global_load_lds(
                (const __attribute__((address_space(1))) void*)(pa + off),
                (__attribute__((address_space(3))) void*)(lA + lbase), 16, 0, 0);
            __builtin_amdgcn_global_load_lds(
                (const __attribute__((address_space(1))) void*)(pb + off),
                (__attribute__((address_space(3))) void*)(lB + lbase), 16, 0, 0);
        }
        pa += 16384;
        pb += 16384;
        __syncthreads();

        // ---- LDS -> fragments (identical to round 1, measured 0 conflicts) ----
        int32x4 af[4][2], bf[4][2];
#pragma unroll
        for (int mf = 0; mf < 4; ++mf)
#pragma unroll
            for (int kk = 0; kk < 2; ++kk) {
                int row = wr * 64 + mf * 16 + lnlo;
                int ch = kk * 4 + lnhi;
                af[mf][kk] = *(const int32x4*)(lA + row * 128 + ((ch ^ (row & 7)) * 16));
            }
#pragma unroll
        for (int nf = 0; nf < 4; ++nf)
#pragma unroll
            for (int kk = 0; kk < 2; ++kk) {
                int col = wc * 64 + nf * 16 + lnlo;
                int ch = kk * 4 + lnhi;
                bf[nf][kk] = *(const int32x4*)(lB + col * 128 + ((ch ^ (col & 7)) * 16));
            }

        // ---- MFMA ----
#pragma unroll
        for (int kk = 0; kk < 2; ++kk)
#pragma unroll
            for (int mf = 0; mf < 4; ++mf)
#pragma unroll
                for (int nf = 0; nf < 4; ++nf)
                    acc[mf][nf] = __builtin_amdgcn_mfma_i32_16x16x64_i8(
                        af[mf][kk], bf[nf][kk], acc[mf][nf], 0, 0, 0);
        __syncthreads();
    }

    // ---- epilogue ----
    float sa = sa_ptr[0];
    float sw = wmax_ptr[0] / 7.0f;  // weight_scale
    float sab = sa * sw;
    float s2v = FIRST ? s2_ptr[0] : 0.f;

    // hq destination block (GEMM1): [mblk][fblk] = [blockIdx.y][blockIdx.x]
    char* hblk = FIRST ? out8 + (((size_t)blockIdx.y * gridDim.x + blockIdx.x) << 14)
                       : nullptr;

#pragma unroll
    for (int nf = 0; nf < 4; ++nf) {
        int lc = wc * 64 + nf * 16 + lnlo;               // local col 0..127
        long col = (long)blockIdx.x * 128 + lc;          // global col
        float bq = rintf(bias[col] / sab) * sab;         // Int32Bias fake-quant
#pragma unroll
        for (int mf = 0; mf < 4; ++mf) {
            int lr0 = wr * 64 + mf * 16 + (lnhi << 2);   // local row base
#pragma unroll
            for (int i = 0; i < 4; ++i) {
                int lr = lr0 + i;
                float h = sab * (float)acc[mf][nf][i] + bq;
                if constexpr (FIRST) {
                    h = fmaxf(h, 0.f);
                    float qv = fminf(fmaxf(rintf(h / s2v), 0.f), 15.f);
                    // blocked-preswizzled store: stored[lr][c]=orig[lr][c^(lr&7)]
                    hblk[lr * 128 + (((lc >> 4) ^ (lr & 7)) << 4) + (lc & 15)] =
                        (char)(int)qv;
                } else {
                    outf[((long)blockIdx.y * 128 + lr) * N + col] = h;
                }
            }
        }
    }
}

// ---------------------------------------------------------------------------
// launch
// ---------------------------------------------------------------------------
extern "C" void kernel_launch(void* const* d_in, const int* in_sizes, int n_in,
                              void* d_out, int out_size, void* d_ws, size_t ws_size,
                              hipStream_t stream) {
    const float* x  = (const float*)d_in[0];   // [4,2048,2048] -> [8192,2048]
    const float* W1 = (const float*)d_in[1];   // [8192,2048]
    const float* b1 = (const float*)d_in[2];   // [8192]
    const float* W2 = (const float*)d_in[3];   // [2048,8192]
    const float* b2 = (const float*)d_in[4];   // [2048]
    const float* s1 = (const float*)d_in[5];
    const float* s2 = (const float*)d_in[6];

    const int M = 8192, D = 2048, F = 8192;

    char* ws = (char*)d_ws;
    unsigned* mx1 = (unsigned*)ws;        // maxabs(W1) as float bits
    unsigned* mx2 = (unsigned*)(ws + 4);  // maxabs(W2)
    char* xq  = ws + 256;                  // [M/128][D/128][16384]
    char* w1q = xq + (size_t)M * D;        // [F/128][D/128][16384]
    char* w2q = w1q + (size_t)F * D;       // [D/128][F/128][16384]
    char* hq  = w2q + (size_t)D * F;       // [M/128][F/128][16384]

    hipMemsetAsync(d_ws, 0, 8, stream);   // zero the maxabs slots

    maxabs_kernel<<<2048, 256, 0, stream>>>(W1, (F * D) >> 2, mx1);
    maxabs_kernel<<<2048, 256, 0, stream>>>(W2, (D * F) >> 2, mx2);

    // blocked-preswizzled quant: kshift = log2(K/128)
    quant_blocked_kernel<<<2048, 256, 0, stream>>>(
        x,  (M * D) >> 2, D, 4, s1, 1.f, -8.f, 7.f, (int*)xq);
    quant_blocked_kernel<<<2048, 256, 0, stream>>>(
        W1, (F * D) >> 2, D, 4, (const float*)mx1, 7.f, -8.f, 7.f, (int*)w1q);
    quant_blocked_kernel<<<2048, 256, 0, stream>>>(
        W2, (D * F) >> 2, F, 6, (const float*)mx2, 7.f, -8.f, 7.f, (int*)w2q);

    // h_q = clip(round(relu(x_q W1_q^T + b1_q)/s2),0,15) -> blocked int8
    gemm_i8_kernel<true><<<dim3(F / 128, M / 128), 256, 0, stream>>>(
        xq, w1q, F, D / 128, s1, (const float*)mx1, b1, s2, hq, nullptr);

    // out = s2*sw2 * (h_int W2_int^T) + b2_q
    gemm_i8_kernel<false><<<dim3(D / 128, M / 128), 256, 0, stream>>>(
        hq, w2q, D, F / 128, s2, (const float*)mx2, b2, nullptr, nullptr,
        (float*)d_out);
}